// Round 2
// baseline (244.605 us; speedup 1.0000x reference)
//
#include <hip/hip_runtime.h>

typedef unsigned short u16;
typedef __attribute__((ext_vector_type(4))) unsigned short u16x4;
typedef __attribute__((ext_vector_type(8))) short short8;
typedef __attribute__((ext_vector_type(4))) float f32x4;

#define MFMA16(a, b, c) __builtin_amdgcn_mfma_f32_16x16x32_bf16(a, b, c, 0, 0, 0)

__device__ __forceinline__ u16 f2bf(float f) {
  unsigned u = __builtin_bit_cast(unsigned, f);
  u += 0x7fffu + ((u >> 16) & 1u);
  return (u16)(u >> 16);
}

__device__ __forceinline__ void gl_lds16(const void* g, void* l) {
  __builtin_amdgcn_global_load_lds((const __attribute__((address_space(1))) char*)g,
                                   (__attribute__((address_space(3))) char*)l, 16, 0, 0);
}

// ---------------- f32 -> bf16 convert (elementwise) ----------------
__global__ __launch_bounds__(256) void cvt_bf16_k(const float* __restrict__ in,
                                                  u16* __restrict__ out) {
  int i = blockIdx.x * 256 + threadIdx.x;  // one float4 per thread, exact cover
  float4 v = ((const float4*)in)[i];
  u16x4 o;
  o.x = f2bf(v.x); o.y = f2bf(v.y); o.z = f2bf(v.z); o.w = f2bf(v.w);
  ((u16x4*)out)[i] = o;
}

// ---------------- W[k][n] f32 -> Wt[n][k] bf16 (tiled transpose) ----------------
__global__ __launch_bounds__(256) void wt_k(const float* __restrict__ W0, const float* __restrict__ W1,
                                            const float* __restrict__ W2, const float* __restrict__ W3,
                                            u16* __restrict__ T0, u16* __restrict__ T1,
                                            u16* __restrict__ T2, u16* __restrict__ T3) {
  const float* W; u16* T;
  switch (blockIdx.z) {
    case 0: W = W0; T = T0; break;
    case 1: W = W1; T = T1; break;
    case 2: W = W2; T = T2; break;
    default: W = W3; T = T3; break;
  }
  __shared__ __align__(16) u16 t[64][72];
  const int k0 = blockIdx.y * 64, n0 = blockIdx.x * 64;
  const int tid = threadIdx.x;
  const int r = tid >> 4, c4 = (tid & 15) * 4;
#pragma unroll
  for (int i = 0; i < 4; i++) {
    float4 v = *(const float4*)(W + (k0 + r + i * 16) * 1024 + n0 + c4);
    u16x4 o;
    o.x = f2bf(v.x); o.y = f2bf(v.y); o.z = f2bf(v.z); o.w = f2bf(v.w);
    *(u16x4*)&t[r + i * 16][c4] = o;
  }
  __syncthreads();
#pragma unroll
  for (int i = 0; i < 4; i++) {
    int nr = r + i * 16;
    u16x4 o;
    o.x = t[c4 + 0][nr]; o.y = t[c4 + 1][nr]; o.z = t[c4 + 2][nr]; o.w = t[c4 + 3][nr];
    *(u16x4*)(T + (n0 + nr) * 1024 + k0 + c4) = o;
  }
}

// ---------------- bf16 GEMM, 128x128 tile, BK=32 (m97 structure) ----------------
// A: [4096][1024] bf16 row-major (K contiguous). Bt: [1024][1024] bf16, Bt[n][k].
// mode 0: Q-proj  -> out bf16 [B][H][1024][64], value=(acc+bias)*0.125
// mode 1: K-proj  -> out bf16 [B][H][1024][64]
// mode 2: V-proj  -> computes C^T, out bf16 [B][H][64][1024]  (V transposed)
// mode 3: O-proj  -> out f32 [4096][1024], value=acc+bias
__global__ __launch_bounds__(256, 2) void gemm_k(const u16* __restrict__ A,
                                                 const u16* __restrict__ Bt,
                                                 const float* __restrict__ bias,
                                                 void* __restrict__ outp, int mode) {
  __shared__ __align__(16) u16 As[128 * 32];
  __shared__ __align__(16) u16 Bs[128 * 32];
  const int tid = threadIdx.x;
  const int l = tid & 63, w = tid >> 6;
  const int lr = l >> 4, lc = l & 15;
  const int wr = w >> 1, wc = w & 1;
  const int m0 = blockIdx.y * 128, n0 = blockIdx.x * 128;

  f32x4 acc[4][4] = {};

  const int sr = tid >> 2, sc = (tid & 3) * 8;
  const u16* Ag = A + (m0 + sr) * 1024 + sc;
  const u16* Bg = Bt + (n0 + sr) * 1024 + sc;
  u16* AsW = As + tid * 8;
  u16* BsW = Bs + tid * 8;

  for (int k0 = 0; k0 < 1024; k0 += 32) {
    __syncthreads();
    gl_lds16(Ag + k0, AsW);
    gl_lds16(Ag + 64 * 1024 + k0, AsW + 2048);
    gl_lds16(Bg + k0, BsW);
    gl_lds16(Bg + 64 * 1024 + k0, BsW + 2048);
    __syncthreads();
    const u16* PA = (mode == 2) ? Bs : As;
    const u16* PB = (mode == 2) ? As : Bs;
    short8 af[4], bf[4];
    const int ks8 = lr * 8;
#pragma unroll
    for (int m = 0; m < 4; m++)
      af[m] = *(const short8*)(PA + (wr * 64 + m * 16 + lc) * 32 + ks8);
#pragma unroll
    for (int n = 0; n < 4; n++)
      bf[n] = *(const short8*)(PB + (wc * 64 + n * 16 + lc) * 32 + ks8);
#pragma unroll
    for (int m = 0; m < 4; m++)
#pragma unroll
      for (int n = 0; n < 4; n++)
        acc[m][n] = MFMA16(af[m], bf[n], acc[m][n]);
  }

  if (mode == 2) {
    u16* outb = (u16*)outp;
#pragma unroll
    for (int m = 0; m < 4; m++) {
#pragma unroll
      for (int r = 0; r < 4; r++) {
        int ncol = n0 + wr * 64 + m * 16 + lr * 4 + r;  // output channel (h*64+d)
        float bb = bias[ncol];
        int h = ncol >> 6, d = ncol & 63;
#pragma unroll
        for (int n = 0; n < 4; n++) {
          int tok = m0 + wc * 64 + n * 16 + lc;  // token (within one batch per tile)
          float v = acc[m][n][r] + bb;
          outb[(((tok >> 10) * 16 + h) * 64 + d) * 1024 + (tok & 1023)] = f2bf(v);
        }
      }
    }
  } else if (mode == 3) {
    float* outf = (float*)outp;
#pragma unroll
    for (int m = 0; m < 4; m++)
#pragma unroll
      for (int n = 0; n < 4; n++) {
        int ncol = n0 + wc * 64 + n * 16 + lc;
        float bb = bias[ncol];
#pragma unroll
        for (int r = 0; r < 4; r++) {
          int tok = m0 + wr * 64 + m * 16 + lr * 4 + r;
          outf[tok * 1024 + ncol] = acc[m][n][r] + bb;
        }
      }
  } else {
    u16* outb = (u16*)outp;
    const float scale = (mode == 0) ? 0.125f : 1.0f;
#pragma unroll
    for (int m = 0; m < 4; m++)
#pragma unroll
      for (int n = 0; n < 4; n++) {
        int ncol = n0 + wc * 64 + n * 16 + lc;
        float bb = bias[ncol];
        int h = ncol >> 6, d = ncol & 63;
#pragma unroll
        for (int r = 0; r < 4; r++) {
          int tok = m0 + wr * 64 + m * 16 + lr * 4 + r;
          float v = (acc[m][n][r] + bb) * scale;
          outb[(((tok >> 10) * 16 + h) * 1024 + (tok & 1023)) * 64 + d] = f2bf(v);
        }
      }
  }
}

// ---------------- flash attention (swapped-QK, in-lane softmax) ----------------
// Q,K: [B*H][1024][64] bf16 (Q pre-scaled by 1/8). Vt: [B*H][64][1024] bf16.
// O: [4096][1024] bf16 (token-major, col = h*64+d).
// Grid: 1024 blocks x 256 thr. Each wave owns 16 q-rows; block owns 64.
// XCD swizzle: heads with h%8==xcd land on one XCD -> K/V (2MB) L2-resident.
__global__ __launch_bounds__(256, 4) void attn_k(const u16* __restrict__ Q,
                                                 const u16* __restrict__ K,
                                                 const u16* __restrict__ Vt,
                                                 u16* __restrict__ O) {
  const int bid = blockIdx.x;
  const int xcd = bid & 7, j = bid >> 3;
  const int bh = xcd + 8 * (j & 7);   // 8 head-groups per XCD
  const int q0 = (j >> 3) * 64;       // 16 q-blocks
  const int tid = threadIdx.x;
  const int w = tid >> 6, l = tid & 63;
  const int lr = l >> 4, lc = l & 15;
  const u16* Qh = Q + bh * (1024 * 64);
  const u16* Kh = K + bh * (1024 * 64);
  const u16* Vh = Vt + bh * (64 * 1024);

  __shared__ __align__(16) u16 Plds[4][16][72];  // per-wave P tile [q][k], padded

  // hoist Q fragments: B-operand rows = q (this wave's 16 rows)
  short8 bq[2];
#pragma unroll
  for (int ks = 0; ks < 2; ks++)
    bq[ks] = *(const short8*)(Qh + (q0 + w * 16 + lc) * 64 + ks * 32 + lr * 8);

  f32x4 oacc[4] = {};
  float mrun = -1e30f, lrun = 0.f;  // per-lane: q = lc

  for (int kv0 = 0; kv0 < 1024; kv0 += 64) {
    // S^T = K . Q^T : rows = k (64 -> 4 frags), cols = q (16)
    f32x4 s[4] = {};
#pragma unroll
    for (int mk = 0; mk < 4; mk++)
#pragma unroll
      for (int ks = 0; ks < 2; ks++) {
        short8 ak = *(const short8*)(Kh + (kv0 + mk * 16 + lc) * 64 + ks * 32 + lr * 8);
        s[mk] = MFMA16(ak, bq[ks], s[mk]);
      }
    // in-lane max over 16 P-values (this lane's k-slice of column q=lc)
    float mx = s[0][0];
#pragma unroll
    for (int mk = 0; mk < 4; mk++)
#pragma unroll
      for (int r = 0; r < 4; r++) mx = fmaxf(mx, s[mk][r]);
    mx = fmaxf(mx, __shfl_xor(mx, 16));
    mx = fmaxf(mx, __shfl_xor(mx, 32));
    float mnew = fmaxf(mrun, mx);
    float alpha = __expf(mrun - mnew);
    mrun = mnew;
    float ps = 0.f;
#pragma unroll
    for (int mk = 0; mk < 4; mk++)
#pragma unroll
      for (int r = 0; r < 4; r++) {
        float p = __expf(s[mk][r] - mnew);
        s[mk][r] = p;
        ps += p;
      }
    ps += __shfl_xor(ps, 16);
    ps += __shfl_xor(ps, 32);
    lrun = lrun * alpha + ps;
    // P -> LDS as [q][k] (per-wave region, same-wave write->read)
#pragma unroll
    for (int mk = 0; mk < 4; mk++)
#pragma unroll
      for (int r = 0; r < 4; r++)
        Plds[w][lc][mk * 16 + lr * 4 + r] = f2bf(s[mk][r]);
    // rescale O: oacc rows are q = lr*4+r -> fetch alpha from lane lc=q'
    float alr[4];
#pragma unroll
    for (int r = 0; r < 4; r++) alr[r] = __shfl(alpha, lr * 4 + r);
#pragma unroll
    for (int nd = 0; nd < 4; nd++)
#pragma unroll
      for (int r = 0; r < 4; r++) oacc[nd][r] *= alr[r];
    // O += P V : A = P[q][k] from LDS, B = Vt rows [d][k]
#pragma unroll
    for (int ks = 0; ks < 2; ks++) {
      short8 ap = *(const short8*)(&Plds[w][lc][ks * 32 + lr * 8]);
#pragma unroll
      for (int nd = 0; nd < 4; nd++) {
        short8 bv = *(const short8*)(Vh + (nd * 16 + lc) * 1024 + kv0 + ks * 32 + lr * 8);
        oacc[nd] = MFMA16(ap, bv, oacc[nd]);
      }
    }
  }
  // epilogue: O /= l, write bf16 [tok][h*64+d]
  float inv = 1.f / lrun;  // for q = lc
  float invr[4];
#pragma unroll
  for (int r = 0; r < 4; r++) invr[r] = __shfl(inv, lr * 4 + r);
  const int b = bh >> 4, h = bh & 15;
#pragma unroll
  for (int r = 0; r < 4; r++) {
    int row = b * 1024 + q0 + w * 16 + lr * 4 + r;
#pragma unroll
    for (int nd = 0; nd < 4; nd++)
      O[row * 1024 + h * 64 + nd * 16 + lc] = f2bf(oacc[nd][r] * invr[r]);
  }
}

// ---------------- residual + LayerNorm ----------------
__global__ __launch_bounds__(256) void ln_k(const float* __restrict__ q,
                                            const float* __restrict__ p2,
                                            const float* __restrict__ gamma,
                                            const float* __restrict__ beta,
                                            float* __restrict__ out) {
  const int row = blockIdx.x, tid = threadIdx.x;
  float4 xq = ((const float4*)(q + row * 1024))[tid];
  float4 xp = ((const float4*)(p2 + row * 1024))[tid];
  float4 x = {xq.x + xp.x, xq.y + xp.y, xq.z + xp.z, xq.w + xp.w};
  float s = x.x + x.y + x.z + x.w;
#pragma unroll
  for (int off = 1; off < 64; off <<= 1) s += __shfl_xor(s, off);
  __shared__ float red[8];
  const int w = tid >> 6;
  if ((tid & 63) == 0) red[w] = s;
  __syncthreads();
  float mu = (red[0] + red[1] + red[2] + red[3]) * (1.0f / 1024.0f);
  float4 dx = {x.x - mu, x.y - mu, x.z - mu, x.w - mu};
  float s2 = dx.x * dx.x + dx.y * dx.y + dx.z * dx.z + dx.w * dx.w;
#pragma unroll
  for (int off = 1; off < 64; off <<= 1) s2 += __shfl_xor(s2, off);
  if ((tid & 63) == 0) red[4 + w] = s2;
  __syncthreads();
  float var = (red[4] + red[5] + red[6] + red[7]) * (1.0f / 1024.0f);
  float rs = rsqrtf(var + 1e-5f);
  float4 g = ((const float4*)gamma)[tid];
  float4 bb = ((const float4*)beta)[tid];
  float4 o = {dx.x * rs * g.x + bb.x, dx.y * rs * g.y + bb.y,
              dx.z * rs * g.z + bb.z, dx.w * rs * g.w + bb.w};
  ((float4*)(out + row * 1024))[tid] = o;
}

extern "C" void kernel_launch(void* const* d_in, const int* in_sizes, int n_in,
                              void* d_out, int out_size, void* d_ws, size_t ws_size,
                              hipStream_t stream) {
  const float* query = (const float*)d_in[0];
  const float* kv    = (const float*)d_in[1];
  const float* Wq = (const float*)d_in[2];
  const float* bq = (const float*)d_in[3];
  const float* Wk = (const float*)d_in[4];
  const float* bk = (const float*)d_in[5];
  const float* Wv = (const float*)d_in[6];
  const float* bv = (const float*)d_in[7];
  const float* Wo = (const float*)d_in[8];
  const float* bo = (const float*)d_in[9];
  const float* gamma = (const float*)d_in[10];
  const float* beta  = (const float*)d_in[11];
  float* out = (float*)d_out;

  char* ws = (char*)d_ws;
  const size_t MB = 1u << 20;
  u16* qbf  = (u16*)(ws + 0 * MB);
  u16* kvbf = (u16*)(ws + 8 * MB);
  u16* Wqt  = (u16*)(ws + 16 * MB);
  u16* Wkt  = (u16*)(ws + 18 * MB);
  u16* Wvt  = (u16*)(ws + 20 * MB);
  u16* Wot  = (u16*)(ws + 22 * MB);
  u16* Qh   = (u16*)(ws + 24 * MB);
  u16* Kh   = (u16*)(ws + 32 * MB);
  u16* Vth  = (u16*)(ws + 40 * MB);
  u16* attO = (u16*)(ws + 48 * MB);
  float* p2 = (float*)(ws + 56 * MB);

  cvt_bf16_k<<<dim3(4096), dim3(256), 0, stream>>>(query, qbf);
  cvt_bf16_k<<<dim3(4096), dim3(256), 0, stream>>>(kv, kvbf);
  wt_k<<<dim3(16, 16, 4), dim3(256), 0, stream>>>(Wq, Wk, Wv, Wo, Wqt, Wkt, Wvt, Wot);

  gemm_k<<<dim3(8, 32), dim3(256), 0, stream>>>(qbf,  Wqt, bq, (void*)Qh,  0);
  gemm_k<<<dim3(8, 32), dim3(256), 0, stream>>>(kvbf, Wkt, bk, (void*)Kh,  1);
  gemm_k<<<dim3(8, 32), dim3(256), 0, stream>>>(kvbf, Wvt, bv, (void*)Vth, 2);

  attn_k<<<dim3(1024), dim3(256), 0, stream>>>(Qh, Kh, Vth, attO);

  gemm_k<<<dim3(8, 32), dim3(256), 0, stream>>>(attO, Wot, bo, (void*)p2, 3);

  ln_k<<<dim3(4096), dim3(256), 0, stream>>>(query, p2, gamma, beta, out);
}

// Round 3
// 216.656 us; speedup vs baseline: 1.1290x; 1.1290x over previous
//
#include <hip/hip_runtime.h>

typedef unsigned short u16;
typedef unsigned int u32;
typedef __attribute__((ext_vector_type(4))) unsigned short u16x4;
typedef __attribute__((ext_vector_type(8))) short short8;
typedef __attribute__((ext_vector_type(4))) float f32x4;

#define MFMA16(a, b, c) __builtin_amdgcn_mfma_f32_16x16x32_bf16(a, b, c, 0, 0, 0)

__device__ __forceinline__ u16 f2bf(float f) {
  unsigned u = __builtin_bit_cast(unsigned, f);
  u += 0x7fffu + ((u >> 16) & 1u);
  return (u16)(u >> 16);
}

__device__ __forceinline__ u32 cvtpk(float lo, float hi) {
  u32 r;
  asm("v_cvt_pk_bf16_f32 %0, %1, %2" : "=v"(r) : "v"(lo), "v"(hi));
  return r;
}

__device__ __forceinline__ void gl_lds16(const void* g, void* l) {
  __builtin_amdgcn_global_load_lds((const __attribute__((address_space(1))) char*)g,
                                   (__attribute__((address_space(3))) char*)l, 16, 0, 0);
}

// ---------------- f32 -> bf16 convert (elementwise) ----------------
__global__ __launch_bounds__(256) void cvt_bf16_k(const float* __restrict__ in,
                                                  u16* __restrict__ out) {
  int i = blockIdx.x * 256 + threadIdx.x;
  float4 v = ((const float4*)in)[i];
  u16x4 o;
  o.x = f2bf(v.x); o.y = f2bf(v.y); o.z = f2bf(v.z); o.w = f2bf(v.w);
  ((u16x4*)out)[i] = o;
}

// ---------------- W[k][n] f32 -> Wt[n][k] bf16 (tiled transpose) ----------------
__global__ __launch_bounds__(256) void wt_k(const float* __restrict__ W0, const float* __restrict__ W1,
                                            const float* __restrict__ W2, const float* __restrict__ W3,
                                            u16* __restrict__ T0, u16* __restrict__ T1,
                                            u16* __restrict__ T2, u16* __restrict__ T3) {
  const float* W; u16* T;
  switch (blockIdx.z) {
    case 0: W = W0; T = T0; break;
    case 1: W = W1; T = T1; break;
    case 2: W = W2; T = T2; break;
    default: W = W3; T = T3; break;
  }
  __shared__ __align__(16) u16 t[64][72];
  const int k0 = blockIdx.y * 64, n0 = blockIdx.x * 64;
  const int tid = threadIdx.x;
  const int r = tid >> 4, c4 = (tid & 15) * 4;
#pragma unroll
  for (int i = 0; i < 4; i++) {
    float4 v = *(const float4*)(W + (k0 + r + i * 16) * 1024 + n0 + c4);
    u16x4 o;
    o.x = f2bf(v.x); o.y = f2bf(v.y); o.z = f2bf(v.z); o.w = f2bf(v.w);
    *(u16x4*)&t[r + i * 16][c4] = o;
  }
  __syncthreads();
#pragma unroll
  for (int i = 0; i < 4; i++) {
    int nr = r + i * 16;
    u16x4 o;
    o.x = t[c4 + 0][nr]; o.y = t[c4 + 1][nr]; o.z = t[c4 + 2][nr]; o.w = t[c4 + 3][nr];
    *(u16x4*)(T + (n0 + nr) * 1024 + k0 + c4) = o;
  }
}

// ---------------- fused QKV projection, 128x64 tile, BK=32 ----------------
// z=0: Q -> Qh bf16 [B][H][1024][64] scaled by 1/8
// z=1: K -> Kh bf16 [B][H][1024][64]
// z=2: V -> Vth bf16 [B][H][64][1024] (transposed write)
__global__ __launch_bounds__(256, 4) void gemmqkv_k(
    const u16* __restrict__ qbf, const u16* __restrict__ kvbf,
    const u16* __restrict__ Wqt, const u16* __restrict__ Wkt, const u16* __restrict__ Wvt,
    const float* __restrict__ pbq, const float* __restrict__ pbk, const float* __restrict__ pbv,
    u16* __restrict__ Qh, u16* __restrict__ Kh, u16* __restrict__ Vth) {
  const int z = blockIdx.z;
  const u16* A  = (z == 0) ? qbf : kvbf;
  const u16* Bt = (z == 0) ? Wqt : (z == 1 ? Wkt : Wvt);
  const float* bias = (z == 0) ? pbq : (z == 1 ? pbk : pbv);

  __shared__ __align__(16) u16 As[128 * 32];
  __shared__ __align__(16) u16 Bs[64 * 32];
  const int tid = threadIdx.x;
  const int l = tid & 63, w = tid >> 6;
  const int lr = l >> 4, lc = l & 15;
  const int wr = w >> 1, wc = w & 1;
  const int m0 = blockIdx.y * 128, n0 = blockIdx.x * 64;

  f32x4 acc[4][2] = {};
  const int sc = (tid & 3) * 8;
  const u16* Ag = A + (m0 + (tid >> 2)) * 1024 + sc;
  const u16* Bg = Bt + (n0 + (tid >> 2)) * 1024 + sc;

  for (int k0 = 0; k0 < 1024; k0 += 32) {
    __syncthreads();
    gl_lds16(Ag + k0, As + tid * 8);
    gl_lds16(Ag + 64 * 1024 + k0, As + 2048 + tid * 8);
    gl_lds16(Bg + k0, Bs + tid * 8);
    __syncthreads();
    short8 af[4], bf[2];
    const int ks8 = lr * 8;
#pragma unroll
    for (int m = 0; m < 4; m++)
      af[m] = *(const short8*)(As + (wr * 64 + m * 16 + lc) * 32 + ks8);
#pragma unroll
    for (int n = 0; n < 2; n++)
      bf[n] = *(const short8*)(Bs + (wc * 32 + n * 16 + lc) * 32 + ks8);
#pragma unroll
    for (int m = 0; m < 4; m++)
#pragma unroll
      for (int n = 0; n < 2; n++)
        acc[m][n] = MFMA16(af[m], bf[n], acc[m][n]);
  }

  if (z < 2) {
    u16* outb = (z == 0) ? Qh : Kh;
    const float scale = (z == 0) ? 0.125f : 1.0f;
#pragma unroll
    for (int m = 0; m < 4; m++)
#pragma unroll
      for (int n = 0; n < 2; n++) {
        int ncol = n0 + wc * 32 + n * 16 + lc;
        float bb = bias[ncol];
        int h = ncol >> 6, d = ncol & 63;
#pragma unroll
        for (int r = 0; r < 4; r++) {
          int tok = m0 + wr * 64 + m * 16 + lr * 4 + r;
          outb[(((tok >> 10) * 16 + h) * 1024 + (tok & 1023)) * 64 + d] =
              f2bf((acc[m][n][r] + bb) * scale);
        }
      }
  } else {
#pragma unroll
    for (int m = 0; m < 4; m++)
#pragma unroll
      for (int n = 0; n < 2; n++) {
        int ncol = n0 + wc * 32 + n * 16 + lc;
        float bb = bias[ncol];
        int h = ncol >> 6, d = ncol & 63;
#pragma unroll
        for (int r = 0; r < 4; r++) {
          int tok = m0 + wr * 64 + m * 16 + lr * 4 + r;
          Vth[(((tok >> 10) * 16 + h) * 64 + d) * 1024 + (tok & 1023)] =
              f2bf(acc[m][n][r] + bb);
        }
      }
  }
}

// ---------------- output projection, 128x64 tile -> f32 ----------------
__global__ __launch_bounds__(256, 4) void gemmo_k(const u16* __restrict__ A,
                                                  const u16* __restrict__ Bt,
                                                  const float* __restrict__ bias,
                                                  float* __restrict__ outf) {
  __shared__ __align__(16) u16 As[128 * 32];
  __shared__ __align__(16) u16 Bs[64 * 32];
  const int tid = threadIdx.x;
  const int l = tid & 63, w = tid >> 6;
  const int lr = l >> 4, lc = l & 15;
  const int wr = w >> 1, wc = w & 1;
  const int m0 = blockIdx.y * 128, n0 = blockIdx.x * 64;

  f32x4 acc[4][2] = {};
  const int sc = (tid & 3) * 8;
  const u16* Ag = A + (m0 + (tid >> 2)) * 1024 + sc;
  const u16* Bg = Bt + (n0 + (tid >> 2)) * 1024 + sc;

  for (int k0 = 0; k0 < 1024; k0 += 32) {
    __syncthreads();
    gl_lds16(Ag + k0, As + tid * 8);
    gl_lds16(Ag + 64 * 1024 + k0, As + 2048 + tid * 8);
    gl_lds16(Bg + k0, Bs + tid * 8);
    __syncthreads();
    short8 af[4], bf[2];
    const int ks8 = lr * 8;
#pragma unroll
    for (int m = 0; m < 4; m++)
      af[m] = *(const short8*)(As + (wr * 64 + m * 16 + lc) * 32 + ks8);
#pragma unroll
    for (int n = 0; n < 2; n++)
      bf[n] = *(const short8*)(Bs + (wc * 32 + n * 16 + lc) * 32 + ks8);
#pragma unroll
    for (int m = 0; m < 4; m++)
#pragma unroll
      for (int n = 0; n < 2; n++)
        acc[m][n] = MFMA16(af[m], bf[n], acc[m][n]);
  }
#pragma unroll
  for (int m = 0; m < 4; m++)
#pragma unroll
    for (int n = 0; n < 2; n++) {
      int ncol = n0 + wc * 32 + n * 16 + lc;
      float bb = bias[ncol];
#pragma unroll
      for (int r = 0; r < 4; r++) {
        int tok = m0 + wr * 64 + m * 16 + lr * 4 + r;
        outf[tok * 1024 + ncol] = acc[m][n][r] + bb;
      }
    }
}

// ---------------- flash attention (swapped-QK, batched reg-resident K/V) ----------------
// Q,K: [B*H][1024][64] bf16 (Q pre-scaled by 1/8). Vt: [B*H][64][1024] bf16.
// O: [4096][1024] bf16. Grid 1024 x 256thr; wave owns 16 q-rows.
// K tile register-resident (prefetched 1 tile ahead); V tile batch-issued under softmax.
__global__ __launch_bounds__(256, 4) void attn_k(const u16* __restrict__ Q,
                                                 const u16* __restrict__ K,
                                                 const u16* __restrict__ Vt,
                                                 u16* __restrict__ O) {
  const int bid = blockIdx.x;
  const int xcd = bid & 7, j = bid >> 3;
  const int bh = xcd + 8 * (j & 7);
  const int q0 = (j >> 3) * 64;
  const int tid = threadIdx.x;
  const int w = tid >> 6, l = tid & 63;
  const int lr = l >> 4, lc = l & 15;
  const u16* Qh = Q + bh * (1024 * 64);
  const u16* Kh = K + bh * (1024 * 64);
  const u16* Vh = Vt + bh * (64 * 1024);

  __shared__ __align__(16) u32 Plds[4][16][36];  // per-wave packed P, u32 = 2 bf16

  short8 bq[2];
#pragma unroll
  for (int ks = 0; ks < 2; ks++)
    bq[ks] = *(const short8*)(Qh + (q0 + w * 16 + lc) * 64 + ks * 32 + lr * 8);

  f32x4 oacc[4] = {};
  float mrun = -1e30f, lrun = 0.f;  // per-lane: q = lc

  // preload K tile 0 into registers
  short8 ak[8];
#pragma unroll
  for (int mk = 0; mk < 4; mk++)
#pragma unroll
    for (int ks = 0; ks < 2; ks++)
      ak[mk * 2 + ks] = *(const short8*)(Kh + (mk * 16 + lc) * 64 + ks * 32 + lr * 8);

  for (int kv0 = 0; kv0 < 1024; kv0 += 64) {
    // S^T = K . Q^T
    f32x4 s[4] = {};
#pragma unroll
    for (int mk = 0; mk < 4; mk++) {
      s[mk] = MFMA16(ak[mk * 2 + 0], bq[0], s[mk]);
      s[mk] = MFMA16(ak[mk * 2 + 1], bq[1], s[mk]);
    }
    // batch-issue V loads for this tile (consumed after softmax)
    short8 bv[8];
#pragma unroll
    for (int nd = 0; nd < 4; nd++)
#pragma unroll
      for (int ks = 0; ks < 2; ks++)
        bv[nd * 2 + ks] = *(const short8*)(Vh + (nd * 16 + lc) * 1024 + kv0 + ks * 32 + lr * 8);
    // prefetch next K tile (wraps to 0 on last iter; harmless)
    const int kvn = (kv0 + 64) & 1023;
#pragma unroll
    for (int mk = 0; mk < 4; mk++)
#pragma unroll
      for (int ks = 0; ks < 2; ks++)
        ak[mk * 2 + ks] = *(const short8*)(Kh + (kvn + mk * 16 + lc) * 64 + ks * 32 + lr * 8);

    // in-lane softmax over this lane's 16 k-values of q-column lc
    float mx = s[0][0];
#pragma unroll
    for (int mk = 0; mk < 4; mk++)
#pragma unroll
      for (int r = 0; r < 4; r++) mx = fmaxf(mx, s[mk][r]);
    mx = fmaxf(mx, __shfl_xor(mx, 16));
    mx = fmaxf(mx, __shfl_xor(mx, 32));
    float mnew = fmaxf(mrun, mx);
    float alpha = __expf(mrun - mnew);
    mrun = mnew;
    float ps = 0.f;
#pragma unroll
    for (int mk = 0; mk < 4; mk++)
#pragma unroll
      for (int r = 0; r < 4; r++) {
        float p = __expf(s[mk][r] - mnew);
        s[mk][r] = p;
        ps += p;
      }
    ps += __shfl_xor(ps, 16);
    ps += __shfl_xor(ps, 32);
    lrun = lrun * alpha + ps;

    // pack P to bf16 pairs and stage through per-wave LDS (u32 writes)
    u32* PW = &Plds[w][lc][0];
#pragma unroll
    for (int mk = 0; mk < 4; mk++)
#pragma unroll
      for (int rr = 0; rr < 2; rr++)
        PW[mk * 8 + lr * 2 + rr] = cvtpk(s[mk][2 * rr], s[mk][2 * rr + 1]);

    // rescale O (rows q = lr*4+r)
    float alr[4];
#pragma unroll
    for (int r = 0; r < 4; r++) alr[r] = __shfl(alpha, lr * 4 + r);
#pragma unroll
    for (int nd = 0; nd < 4; nd++)
#pragma unroll
      for (int r = 0; r < 4; r++) oacc[nd][r] *= alr[r];

    // O += P V
#pragma unroll
    for (int ks = 0; ks < 2; ks++) {
      short8 ap = *(const short8*)&Plds[w][lc][ks * 16 + lr * 4];
#pragma unroll
      for (int nd = 0; nd < 4; nd++)
        oacc[nd] = MFMA16(ap, bv[nd * 2 + ks], oacc[nd]);
    }
  }

  // epilogue
  float inv = 1.f / lrun;
  float invr[4];
#pragma unroll
  for (int r = 0; r < 4; r++) invr[r] = __shfl(inv, lr * 4 + r);
  const int b = bh >> 4, h = bh & 15;
#pragma unroll
  for (int r = 0; r < 4; r++) {
    int row = b * 1024 + q0 + w * 16 + lr * 4 + r;
#pragma unroll
    for (int nd = 0; nd < 4; nd++)
      O[row * 1024 + h * 64 + nd * 16 + lc] = f2bf(oacc[nd][r] * invr[r]);
  }
}

// ---------------- residual + LayerNorm ----------------
__global__ __launch_bounds__(256) void ln_k(const float* __restrict__ q,
                                            const float* __restrict__ p2,
                                            const float* __restrict__ gamma,
                                            const float* __restrict__ beta,
                                            float* __restrict__ out) {
  const int row = blockIdx.x, tid = threadIdx.x;
  float4 xq = ((const float4*)(q + row * 1024))[tid];
  float4 xp = ((const float4*)(p2 + row * 1024))[tid];
  float4 x = {xq.x + xp.x, xq.y + xp.y, xq.z + xp.z, xq.w + xp.w};
  float s = x.x + x.y + x.z + x.w;
#pragma unroll
  for (int off = 1; off < 64; off <<= 1) s += __shfl_xor(s, off);
  __shared__ float red[8];
  const int w = tid >> 6;
  if ((tid & 63) == 0) red[w] = s;
  __syncthreads();
  float mu = (red[0] + red[1] + red[2] + red[3]) * (1.0f / 1024.0f);
  float4 dx = {x.x - mu, x.y - mu, x.z - mu, x.w - mu};
  float s2 = dx.x * dx.x + dx.y * dx.y + dx.z * dx.z + dx.w * dx.w;
#pragma unroll
  for (int off = 1; off < 64; off <<= 1) s2 += __shfl_xor(s2, off);
  if ((tid & 63) == 0) red[4 + w] = s2;
  __syncthreads();
  float var = (red[4] + red[5] + red[6] + red[7]) * (1.0f / 1024.0f);
  float rs = rsqrtf(var + 1e-5f);
  float4 g = ((const float4*)gamma)[tid];
  float4 bb = ((const float4*)beta)[tid];
  float4 o = {dx.x * rs * g.x + bb.x, dx.y * rs * g.y + bb.y,
              dx.z * rs * g.z + bb.z, dx.w * rs * g.w + bb.w};
  ((float4*)(out + row * 1024))[tid] = o;
}

extern "C" void kernel_launch(void* const* d_in, const int* in_sizes, int n_in,
                              void* d_out, int out_size, void* d_ws, size_t ws_size,
                              hipStream_t stream) {
  const float* query = (const float*)d_in[0];
  const float* kv    = (const float*)d_in[1];
  const float* Wq = (const float*)d_in[2];
  const float* bq = (const float*)d_in[3];
  const float* Wk = (const float*)d_in[4];
  const float* bk = (const float*)d_in[5];
  const float* Wv = (const float*)d_in[6];
  const float* bv = (const float*)d_in[7];
  const float* Wo = (const float*)d_in[8];
  const float* bo = (const float*)d_in[9];
  const float* gamma = (const float*)d_in[10];
  const float* beta  = (const float*)d_in[11];
  float* out = (float*)d_out;

  char* ws = (char*)d_ws;
  const size_t MB = 1u << 20;
  u16* qbf  = (u16*)(ws + 0 * MB);
  u16* kvbf = (u16*)(ws + 8 * MB);
  u16* Wqt  = (u16*)(ws + 16 * MB);
  u16* Wkt  = (u16*)(ws + 18 * MB);
  u16* Wvt  = (u16*)(ws + 20 * MB);
  u16* Wot  = (u16*)(ws + 22 * MB);
  u16* Qh   = (u16*)(ws + 24 * MB);
  u16* Kh   = (u16*)(ws + 32 * MB);
  u16* Vth  = (u16*)(ws + 40 * MB);
  u16* attO = (u16*)(ws + 48 * MB);
  float* p2 = (float*)(ws + 56 * MB);

  cvt_bf16_k<<<dim3(4096), dim3(256), 0, stream>>>(query, qbf);
  cvt_bf16_k<<<dim3(4096), dim3(256), 0, stream>>>(kv, kvbf);
  wt_k<<<dim3(16, 16, 4), dim3(256), 0, stream>>>(Wq, Wk, Wv, Wo, Wqt, Wkt, Wvt, Wot);

  gemmqkv_k<<<dim3(16, 32, 3), dim3(256), 0, stream>>>(qbf, kvbf, Wqt, Wkt, Wvt,
                                                       bq, bk, bv, Qh, Kh, Vth);

  attn_k<<<dim3(1024), dim3(256), 0, stream>>>(Qh, Kh, Vth, attO);

  gemmo_k<<<dim3(16, 32), dim3(256), 0, stream>>>(attO, Wot, bo, p2);

  ln_k<<<dim3(4096), dim3(256), 0, stream>>>(query, p2, gamma, beta, out);
}

// Round 4
// 133.484 us; speedup vs baseline: 1.8325x; 1.6231x over previous
//
#include <hip/hip_runtime.h>

typedef unsigned short u16;
typedef unsigned int u32;
typedef __attribute__((ext_vector_type(4))) unsigned short u16x4;
typedef __attribute__((ext_vector_type(8))) short short8;
typedef __attribute__((ext_vector_type(4))) float f32x4;

#define MFMA16(a, b, c) __builtin_amdgcn_mfma_f32_16x16x32_bf16(a, b, c, 0, 0, 0)

__device__ __forceinline__ u16 f2bf(float f) {
  unsigned u = __builtin_bit_cast(unsigned, f);
  u += 0x7fffu + ((u >> 16) & 1u);
  return (u16)(u >> 16);
}

__device__ __forceinline__ u32 cvtpk(float lo, float hi) {
  u32 r;
  asm("v_cvt_pk_bf16_f32 %0, %1, %2" : "=v"(r) : "v"(lo), "v"(hi));
  return r;
}

__device__ __forceinline__ void gl_lds16(const void* g, void* l) {
  __builtin_amdgcn_global_load_lds((const __attribute__((address_space(1))) char*)g,
                                   (__attribute__((address_space(3))) char*)l, 16, 0, 0);
}

// ---------------- f32 -> bf16 convert (elementwise) ----------------
__global__ __launch_bounds__(256) void cvt_bf16_k(const float* __restrict__ in,
                                                  u16* __restrict__ out) {
  int i = blockIdx.x * 256 + threadIdx.x;
  float4 v = ((const float4*)in)[i];
  u16x4 o;
  o.x = f2bf(v.x); o.y = f2bf(v.y); o.z = f2bf(v.z); o.w = f2bf(v.w);
  ((u16x4*)out)[i] = o;
}

// ---------------- W[k][n] f32 -> Wt[n][k] bf16 (tiled transpose) ----------------
__global__ __launch_bounds__(256) void wt_k(const float* __restrict__ W0, const float* __restrict__ W1,
                                            const float* __restrict__ W2, const float* __restrict__ W3,
                                            u16* __restrict__ T0, u16* __restrict__ T1,
                                            u16* __restrict__ T2, u16* __restrict__ T3) {
  const float* W; u16* T;
  switch (blockIdx.z) {
    case 0: W = W0; T = T0; break;
    case 1: W = W1; T = T1; break;
    case 2: W = W2; T = T2; break;
    default: W = W3; T = T3; break;
  }
  __shared__ __align__(16) u16 t[64][72];
  const int k0 = blockIdx.y * 64, n0 = blockIdx.x * 64;
  const int tid = threadIdx.x;
  const int r = tid >> 4, c4 = (tid & 15) * 4;
#pragma unroll
  for (int i = 0; i < 4; i++) {
    float4 v = *(const float4*)(W + (k0 + r + i * 16) * 1024 + n0 + c4);
    u16x4 o;
    o.x = f2bf(v.x); o.y = f2bf(v.y); o.z = f2bf(v.z); o.w = f2bf(v.w);
    *(u16x4*)&t[r + i * 16][c4] = o;
  }
  __syncthreads();
#pragma unroll
  for (int i = 0; i < 4; i++) {
    int nr = r + i * 16;
    u16x4 o;
    o.x = t[c4 + 0][nr]; o.y = t[c4 + 1][nr]; o.z = t[c4 + 2][nr]; o.w = t[c4 + 3][nr];
    *(u16x4*)(T + (n0 + nr) * 1024 + k0 + c4) = o;
  }
}

// ---------------- fused QKV projection, 128x64 tile, BK=32 ----------------
__global__ __launch_bounds__(256, 4) void gemmqkv_k(
    const u16* __restrict__ qbf, const u16* __restrict__ kvbf,
    const u16* __restrict__ Wqt, const u16* __restrict__ Wkt, const u16* __restrict__ Wvt,
    const float* __restrict__ pbq, const float* __restrict__ pbk, const float* __restrict__ pbv,
    u16* __restrict__ Qh, u16* __restrict__ Kh, u16* __restrict__ Vth) {
  const int z = blockIdx.z;
  const u16* A  = (z == 0) ? qbf : kvbf;
  const u16* Bt = (z == 0) ? Wqt : (z == 1 ? Wkt : Wvt);
  const float* bias = (z == 0) ? pbq : (z == 1 ? pbk : pbv);

  __shared__ __align__(16) u16 As[128 * 32];
  __shared__ __align__(16) u16 Bs[64 * 32];
  const int tid = threadIdx.x;
  const int l = tid & 63, w = tid >> 6;
  const int lr = l >> 4, lc = l & 15;
  const int wr = w >> 1, wc = w & 1;
  const int m0 = blockIdx.y * 128, n0 = blockIdx.x * 64;

  f32x4 acc[4][2] = {};
  const int sc = (tid & 3) * 8;
  const u16* Ag = A + (m0 + (tid >> 2)) * 1024 + sc;
  const u16* Bg = Bt + (n0 + (tid >> 2)) * 1024 + sc;

  for (int k0 = 0; k0 < 1024; k0 += 32) {
    __syncthreads();
    gl_lds16(Ag + k0, As + tid * 8);
    gl_lds16(Ag + 64 * 1024 + k0, As + 2048 + tid * 8);
    gl_lds16(Bg + k0, Bs + tid * 8);
    __syncthreads();
    short8 af[4], bf[2];
    const int ks8 = lr * 8;
#pragma unroll
    for (int m = 0; m < 4; m++)
      af[m] = *(const short8*)(As + (wr * 64 + m * 16 + lc) * 32 + ks8);
#pragma unroll
    for (int n = 0; n < 2; n++)
      bf[n] = *(const short8*)(Bs + (wc * 32 + n * 16 + lc) * 32 + ks8);
#pragma unroll
    for (int m = 0; m < 4; m++)
#pragma unroll
      for (int n = 0; n < 2; n++)
        acc[m][n] = MFMA16(af[m], bf[n], acc[m][n]);
  }

  if (z < 2) {
    u16* outb = (z == 0) ? Qh : Kh;
    const float scale = (z == 0) ? 0.125f : 1.0f;
#pragma unroll
    for (int m = 0; m < 4; m++)
#pragma unroll
      for (int n = 0; n < 2; n++) {
        int ncol = n0 + wc * 32 + n * 16 + lc;
        float bb = bias[ncol];
        int h = ncol >> 6, d = ncol & 63;
#pragma unroll
        for (int r = 0; r < 4; r++) {
          int tok = m0 + wr * 64 + m * 16 + lr * 4 + r;
          outb[(((tok >> 10) * 16 + h) * 1024 + (tok & 1023)) * 64 + d] =
              f2bf((acc[m][n][r] + bb) * scale);
        }
      }
  } else {
#pragma unroll
    for (int m = 0; m < 4; m++)
#pragma unroll
      for (int n = 0; n < 2; n++) {
        int ncol = n0 + wc * 32 + n * 16 + lc;
        float bb = bias[ncol];
        int h = ncol >> 6, d = ncol & 63;
#pragma unroll
        for (int r = 0; r < 4; r++) {
          int tok = m0 + wr * 64 + m * 16 + lr * 4 + r;
          Vth[(((tok >> 10) * 16 + h) * 64 + d) * 1024 + (tok & 1023)] =
              f2bf(acc[m][n][r] + bb);
        }
      }
  }
}

// ---------------- output projection, 128x64 tile -> f32 ----------------
__global__ __launch_bounds__(256, 4) void gemmo_k(const u16* __restrict__ A,
                                                  const u16* __restrict__ Bt,
                                                  const float* __restrict__ bias,
                                                  float* __restrict__ outf) {
  __shared__ __align__(16) u16 As[128 * 32];
  __shared__ __align__(16) u16 Bs[64 * 32];
  const int tid = threadIdx.x;
  const int l = tid & 63, w = tid >> 6;
  const int lr = l >> 4, lc = l & 15;
  const int wr = w >> 1, wc = w & 1;
  const int m0 = blockIdx.y * 128, n0 = blockIdx.x * 64;

  f32x4 acc[4][2] = {};
  const int sc = (tid & 3) * 8;
  const u16* Ag = A + (m0 + (tid >> 2)) * 1024 + sc;
  const u16* Bg = Bt + (n0 + (tid >> 2)) * 1024 + sc;

  for (int k0 = 0; k0 < 1024; k0 += 32) {
    __syncthreads();
    gl_lds16(Ag + k0, As + tid * 8);
    gl_lds16(Ag + 64 * 1024 + k0, As + 2048 + tid * 8);
    gl_lds16(Bg + k0, Bs + tid * 8);
    __syncthreads();
    short8 af[4], bf[2];
    const int ks8 = lr * 8;
#pragma unroll
    for (int m = 0; m < 4; m++)
      af[m] = *(const short8*)(As + (wr * 64 + m * 16 + lc) * 32 + ks8);
#pragma unroll
    for (int n = 0; n < 2; n++)
      bf[n] = *(const short8*)(Bs + (wc * 32 + n * 16 + lc) * 32 + ks8);
#pragma unroll
    for (int m = 0; m < 4; m++)
#pragma unroll
      for (int n = 0; n < 2; n++)
        acc[m][n] = MFMA16(af[m], bf[n], acc[m][n]);
  }
#pragma unroll
  for (int m = 0; m < 4; m++)
#pragma unroll
    for (int n = 0; n < 2; n++) {
      int ncol = n0 + wc * 32 + n * 16 + lc;
      float bb = bias[ncol];
#pragma unroll
      for (int r = 0; r < 4; r++) {
        int tok = m0 + wr * 64 + m * 16 + lr * 4 + r;
        outf[tok * 1024 + ncol] = acc[m][n][r] + bb;
      }
    }
}

// ---------------- flash attention: LDS-staged K/V (async DMA, swizzled) ----------------
// Q,K: [B*H][1024][64] bf16 (Q pre-scaled). Vt: [B*H][64][1024] bf16.
// Block = 4 waves, 64 q-rows; waves SHARE the K/V tile via LDS (staged once/block).
// Swizzle: LDS linear dest + pre-swizzled global source + swizzled read (XOR row&7<<4).
__global__ __launch_bounds__(256, 4) void attn_k(const u16* __restrict__ Q,
                                                 const u16* __restrict__ K,
                                                 const u16* __restrict__ Vt,
                                                 u16* __restrict__ O) {
  const int bid = blockIdx.x;
  const int xcd = bid & 7, j = bid >> 3;
  const int bh = xcd + 8 * (j & 7);
  const int q0 = (j >> 3) * 64;
  const int tid = threadIdx.x;
  const int w = tid >> 6, l = tid & 63;
  const int lr = l >> 4, lc = l & 15;
  const u16* Qh = Q + bh * (1024 * 64);
  const u16* Kh = K + bh * (1024 * 64);
  const u16* Vh = Vt + bh * (64 * 1024);

  __shared__ __align__(16) u16 Ks[64 * 64];   // [kv][d], 128B rows, swizzled cols
  __shared__ __align__(16) u16 Vs[64 * 64];   // [d][kv], 128B rows, swizzled cols
  __shared__ __align__(16) u32 Plds[4][16][36];

  // staging: thread t covers (row, 16B col-block); source col pre-swizzled
  const int st_row = tid >> 3;            // 0..31 (second issue: +32)
  const int st_cb = (tid & 7) * 16;       // byte col in row
  const int sw1 = (st_cb ^ ((st_row & 7) << 4)) >> 1;        // u16 col
  const int st_row2 = st_row + 32;
  const int sw2 = (st_cb ^ ((st_row2 & 7) << 4)) >> 1;

  // hoist Q fragments (B-operand rows = this wave's 16 q-rows)
  short8 bq[2];
#pragma unroll
  for (int ks = 0; ks < 2; ks++)
    bq[ks] = *(const short8*)(Qh + (q0 + w * 16 + lc) * 64 + ks * 32 + lr * 8);

  f32x4 oacc[4] = {};
  float mrun = -1e30f, lrun = 0.f;  // per-lane: q = lc

  for (int kv0 = 0; kv0 < 1024; kv0 += 64) {
    __syncthreads();  // all waves done reading previous tile
    gl_lds16(Kh + (kv0 + st_row) * 64 + sw1, Ks + tid * 8);
    gl_lds16(Kh + (kv0 + st_row2) * 64 + sw2, Ks + 2048 + tid * 8);
    gl_lds16(Vh + st_row * 1024 + kv0 + sw1, Vs + tid * 8);
    gl_lds16(Vh + st_row2 * 1024 + kv0 + sw2, Vs + 2048 + tid * 8);
    __syncthreads();  // vmcnt(0) drain -> tile ready

    // S^T = K . Q^T : rows = k (64), cols = q (16)
    f32x4 s[4] = {};
#pragma unroll
    for (int mk = 0; mk < 4; mk++) {
      const int krow = mk * 16 + lc;
      const u16* kp = Ks + krow * 64;
#pragma unroll
      for (int ks = 0; ks < 2; ks++) {
        const int cb = (ks * 64 + lr * 16) ^ ((krow & 7) << 4);
        short8 ak = *(const short8*)(kp + (cb >> 1));
        s[mk] = MFMA16(ak, bq[ks], s[mk]);
      }
    }

    // in-lane softmax over this lane's 16 k-values of q-column lc
    float mx = s[0][0];
#pragma unroll
    for (int mk = 0; mk < 4; mk++)
#pragma unroll
      for (int r = 0; r < 4; r++) mx = fmaxf(mx, s[mk][r]);
    mx = fmaxf(mx, __shfl_xor(mx, 16));
    mx = fmaxf(mx, __shfl_xor(mx, 32));
    float mnew = fmaxf(mrun, mx);
    float alpha = __expf(mrun - mnew);
    mrun = mnew;
    float ps = 0.f;
#pragma unroll
    for (int mk = 0; mk < 4; mk++)
#pragma unroll
      for (int r = 0; r < 4; r++) {
        float p = __expf(s[mk][r] - mnew);
        s[mk][r] = p;
        ps += p;
      }
    ps += __shfl_xor(ps, 16);
    ps += __shfl_xor(ps, 32);
    lrun = lrun * alpha + ps;

    // pack P to bf16 pairs, stage through per-wave LDS
    u32* PW = &Plds[w][lc][0];
#pragma unroll
    for (int mk = 0; mk < 4; mk++)
#pragma unroll
      for (int rr = 0; rr < 2; rr++)
        PW[mk * 8 + lr * 2 + rr] = cvtpk(s[mk][2 * rr], s[mk][2 * rr + 1]);

    // rescale O (rows q = lr*4+r)
    float alr[4];
#pragma unroll
    for (int r = 0; r < 4; r++) alr[r] = __shfl(alpha, lr * 4 + r);
#pragma unroll
    for (int nd = 0; nd < 4; nd++)
#pragma unroll
      for (int r = 0; r < 4; r++) oacc[nd][r] *= alr[r];

    // O += P V  (V fragments from swizzled LDS)
#pragma unroll
    for (int ks = 0; ks < 2; ks++) {
      short8 ap = *(const short8*)&Plds[w][lc][ks * 16 + lr * 4];
#pragma unroll
      for (int nd = 0; nd < 4; nd++) {
        const int vrow = nd * 16 + lc;
        const int cb = (ks * 64 + lr * 16) ^ ((vrow & 7) << 4);
        short8 bv = *(const short8*)(Vs + vrow * 64 + (cb >> 1));
        oacc[nd] = MFMA16(ap, bv, oacc[nd]);
      }
    }
  }

  // epilogue
  float inv = 1.f / lrun;
  float invr[4];
#pragma unroll
  for (int r = 0; r < 4; r++) invr[r] = __shfl(inv, lr * 4 + r);
  const int b = bh >> 4, h = bh & 15;
#pragma unroll
  for (int r = 0; r < 4; r++) {
    int row = b * 1024 + q0 + w * 16 + lr * 4 + r;
#pragma unroll
    for (int nd = 0; nd < 4; nd++)
      O[row * 1024 + h * 64 + nd * 16 + lc] = f2bf(oacc[nd][r] * invr[r]);
  }
}

// ---------------- residual + LayerNorm ----------------
__global__ __launch_bounds__(256) void ln_k(const float* __restrict__ q,
                                            const float* __restrict__ p2,
                                            const float* __restrict__ gamma,
                                            const float* __restrict__ beta,
                                            float* __restrict__ out) {
  const int row = blockIdx.x, tid = threadIdx.x;
  float4 xq = ((const float4*)(q + row * 1024))[tid];
  float4 xp = ((const float4*)(p2 + row * 1024))[tid];
  float4 x = {xq.x + xp.x, xq.y + xp.y, xq.z + xp.z, xq.w + xp.w};
  float s = x.x + x.y + x.z + x.w;
#pragma unroll
  for (int off = 1; off < 64; off <<= 1) s += __shfl_xor(s, off);
  __shared__ float red[8];
  const int w = tid >> 6;
  if ((tid & 63) == 0) red[w] = s;
  __syncthreads();
  float mu = (red[0] + red[1] + red[2] + red[3]) * (1.0f / 1024.0f);
  float4 dx = {x.x - mu, x.y - mu, x.z - mu, x.w - mu};
  float s2 = dx.x * dx.x + dx.y * dx.y + dx.z * dx.z + dx.w * dx.w;
#pragma unroll
  for (int off = 1; off < 64; off <<= 1) s2 += __shfl_xor(s2, off);
  if ((tid & 63) == 0) red[4 + w] = s2;
  __syncthreads();
  float var = (red[4] + red[5] + red[6] + red[7]) * (1.0f / 1024.0f);
  float rs = rsqrtf(var + 1e-5f);
  float4 g = ((const float4*)gamma)[tid];
  float4 bb = ((const float4*)beta)[tid];
  float4 o = {dx.x * rs * g.x + bb.x, dx.y * rs * g.y + bb.y,
              dx.z * rs * g.z + bb.z, dx.w * rs * g.w + bb.w};
  ((float4*)(out + row * 1024))[tid] = o;
}

extern "C" void kernel_launch(void* const* d_in, const int* in_sizes, int n_in,
                              void* d_out, int out_size, void* d_ws, size_t ws_size,
                              hipStream_t stream) {
  const float* query = (const float*)d_in[0];
  const float* kv    = (const float*)d_in[1];
  const float* Wq = (const float*)d_in[2];
  const float* bq = (const float*)d_in[3];
  const float* Wk = (const float*)d_in[4];
  const float* bk = (const float*)d_in[5];
  const float* Wv = (const float*)d_in[6];
  const float* bv = (const float*)d_in[7];
  const float* Wo = (const float*)d_in[8];
  const float* bo = (const float*)d_in[9];
  const float* gamma = (const float*)d_in[10];
  const float* beta  = (const float*)d_in[11];
  float* out = (float*)d_out;

  char* ws = (char*)d_ws;
  const size_t MB = 1u << 20;
  u16* qbf  = (u16*)(ws + 0 * MB);
  u16* kvbf = (u16*)(ws + 8 * MB);
  u16* Wqt  = (u16*)(ws + 16 * MB);
  u16* Wkt  = (u16*)(ws + 18 * MB);
  u16* Wvt  = (u16*)(ws + 20 * MB);
  u16* Wot  = (u16*)(ws + 22 * MB);
  u16* Qh   = (u16*)(ws + 24 * MB);
  u16* Kh   = (u16*)(ws + 32 * MB);
  u16* Vth  = (u16*)(ws + 40 * MB);
  u16* attO = (u16*)(ws + 48 * MB);
  float* p2 = (float*)(ws + 56 * MB);

  cvt_bf16_k<<<dim3(4096), dim3(256), 0, stream>>>(query, qbf);
  cvt_bf16_k<<<dim3(4096), dim3(256), 0, stream>>>(kv, kvbf);
  wt_k<<<dim3(16, 16, 4), dim3(256), 0, stream>>>(Wq, Wk, Wv, Wo, Wqt, Wkt, Wvt, Wot);

  gemmqkv_k<<<dim3(16, 32, 3), dim3(256), 0, stream>>>(qbf, kvbf, Wqt, Wkt, Wvt,
                                                       bq, bk, bv, Qh, Kh, Vth);

  attn_k<<<dim3(1024), dim3(256), 0, stream>>>(Qh, Kh, Vth, attO);

  gemmo_k<<<dim3(16, 32), dim3(256), 0, stream>>>(attO, Wot, bo, p2);

  ln_k<<<dim3(4096), dim3(256), 0, stream>>>(query, p2, gamma, beta, out);
}

// Round 5
// 116.891 us; speedup vs baseline: 2.0926x; 1.1420x over previous
//
#include <hip/hip_runtime.h>

typedef unsigned short u16;
typedef unsigned int u32;
typedef __attribute__((ext_vector_type(4))) unsigned short u16x4;
typedef __attribute__((ext_vector_type(8))) short short8;
typedef __attribute__((ext_vector_type(4))) float f32x4;

#define MFMA16(a, b, c) __builtin_amdgcn_mfma_f32_16x16x32_bf16(a, b, c, 0, 0, 0)

__device__ __forceinline__ u16 f2bf(float f) {
  unsigned u = __builtin_bit_cast(unsigned, f);
  u += 0x7fffu + ((u >> 16) & 1u);
  return (u16)(u >> 16);
}

__device__ __forceinline__ u32 cvtpk(float lo, float hi) {
  u32 r;
  asm("v_cvt_pk_bf16_f32 %0, %1, %2" : "=v"(r) : "v"(lo), "v"(hi));
  return r;
}

__device__ __forceinline__ void gl_lds16(const void* g, void* l) {
  __builtin_amdgcn_global_load_lds((const __attribute__((address_space(1))) char*)g,
                                   (__attribute__((address_space(3))) char*)l, 16, 0, 0);
}

// ---------------- f32 -> bf16 convert (elementwise) ----------------
__global__ __launch_bounds__(256) void cvt_bf16_k(const float* __restrict__ in,
                                                  u16* __restrict__ out) {
  int i = blockIdx.x * 256 + threadIdx.x;
  float4 v = ((const float4*)in)[i];
  u16x4 o;
  o.x = f2bf(v.x); o.y = f2bf(v.y); o.z = f2bf(v.z); o.w = f2bf(v.w);
  ((u16x4*)out)[i] = o;
}

// ---------------- W[k][n] f32 -> Wt[n][k] bf16 (tiled transpose) ----------------
__global__ __launch_bounds__(256) void wt_k(const float* __restrict__ W0, const float* __restrict__ W1,
                                            const float* __restrict__ W2, const float* __restrict__ W3,
                                            u16* __restrict__ T0, u16* __restrict__ T1,
                                            u16* __restrict__ T2, u16* __restrict__ T3) {
  const float* W; u16* T;
  switch (blockIdx.z) {
    case 0: W = W0; T = T0; break;
    case 1: W = W1; T = T1; break;
    case 2: W = W2; T = T2; break;
    default: W = W3; T = T3; break;
  }
  __shared__ __align__(16) u16 t[64][72];
  const int k0 = blockIdx.y * 64, n0 = blockIdx.x * 64;
  const int tid = threadIdx.x;
  const int r = tid >> 4, c4 = (tid & 15) * 4;
#pragma unroll
  for (int i = 0; i < 4; i++) {
    float4 v = *(const float4*)(W + (k0 + r + i * 16) * 1024 + n0 + c4);
    u16x4 o;
    o.x = f2bf(v.x); o.y = f2bf(v.y); o.z = f2bf(v.z); o.w = f2bf(v.w);
    *(u16x4*)&t[r + i * 16][c4] = o;
  }
  __syncthreads();
#pragma unroll
  for (int i = 0; i < 4; i++) {
    int nr = r + i * 16;
    u16x4 o;
    o.x = t[c4 + 0][nr]; o.y = t[c4 + 1][nr]; o.z = t[c4 + 2][nr]; o.w = t[c4 + 3][nr];
    *(u16x4*)(T + (n0 + nr) * 1024 + k0 + c4) = o;
  }
}

// ---------------- fused QKV projection, 128x128 tile, BK=32, XCD-swizzled ----------------
// grid: 768 linear blocks. swz=(lin%8)*96+lin/8 -> x(8 n-blk), y(32 m-blk), z(3 ops).
// z=0: Q -> Qh bf16 [B][H][1024][64] scaled 1/8; z=1: K; z=2: V^T -> [B][H][64][1024].
__global__ __launch_bounds__(256, 3) void gemmqkv_k(
    const u16* __restrict__ qbf, const u16* __restrict__ kvbf,
    const u16* __restrict__ Wqt, const u16* __restrict__ Wkt, const u16* __restrict__ Wvt,
    const float* __restrict__ pbq, const float* __restrict__ pbk, const float* __restrict__ pbv,
    u16* __restrict__ Qh, u16* __restrict__ Kh, u16* __restrict__ Vth) {
  const int lin = blockIdx.x;
  const int swz = (lin & 7) * 96 + (lin >> 3);
  const int x = swz & 7, y = (swz >> 3) & 31, z = swz >> 8;

  const u16* A  = (z == 0) ? qbf : kvbf;
  const u16* Bt = (z == 0) ? Wqt : (z == 1 ? Wkt : Wvt);
  const float* bias = (z == 0) ? pbq : (z == 1 ? pbk : pbv);

  __shared__ __align__(16) u16 As[128 * 32];
  __shared__ __align__(16) u16 Bs[128 * 32];
  const int tid = threadIdx.x;
  const int l = tid & 63, w = tid >> 6;
  const int lr = l >> 4, lc = l & 15;
  const int wr = w >> 1, wc = w & 1;
  const int m0 = y * 128, n0 = x * 128;

  f32x4 acc[4][4] = {};

  const int sr = tid >> 2, sc = (tid & 3) * 8;
  const u16* Ag = A + (m0 + sr) * 1024 + sc;
  const u16* Bg = Bt + (n0 + sr) * 1024 + sc;
  u16* AsW = As + tid * 8;
  u16* BsW = Bs + tid * 8;

  for (int k0 = 0; k0 < 1024; k0 += 32) {
    __syncthreads();
    gl_lds16(Ag + k0, AsW);
    gl_lds16(Ag + 64 * 1024 + k0, AsW + 2048);
    gl_lds16(Bg + k0, BsW);
    gl_lds16(Bg + 64 * 1024 + k0, BsW + 2048);
    __syncthreads();
    const u16* PA = (z == 2) ? Bs : As;
    const u16* PB = (z == 2) ? As : Bs;
    short8 af[4], bf[4];
    const int ks8 = lr * 8;
#pragma unroll
    for (int m = 0; m < 4; m++)
      af[m] = *(const short8*)(PA + (wr * 64 + m * 16 + lc) * 32 + ks8);
#pragma unroll
    for (int n = 0; n < 4; n++)
      bf[n] = *(const short8*)(PB + (wc * 64 + n * 16 + lc) * 32 + ks8);
#pragma unroll
    for (int m = 0; m < 4; m++)
#pragma unroll
      for (int n = 0; n < 4; n++)
        acc[m][n] = MFMA16(af[m], bf[n], acc[m][n]);
  }

  if (z == 2) {  // V^T: acc rows = channel, cols = token
#pragma unroll
    for (int m = 0; m < 4; m++) {
#pragma unroll
      for (int r = 0; r < 4; r++) {
        int ncol = n0 + wr * 64 + m * 16 + lr * 4 + r;  // channel h*64+d
        float bb = bias[ncol];
        int h = ncol >> 6, d = ncol & 63;
#pragma unroll
        for (int n = 0; n < 4; n++) {
          int tok = m0 + wc * 64 + n * 16 + lc;
          Vth[(((tok >> 10) * 16 + h) * 64 + d) * 1024 + (tok & 1023)] =
              f2bf(acc[m][n][r] + bb);
        }
      }
    }
  } else {
    u16* outb = (z == 0) ? Qh : Kh;
    const float scale = (z == 0) ? 0.125f : 1.0f;
#pragma unroll
    for (int m = 0; m < 4; m++)
#pragma unroll
      for (int n = 0; n < 4; n++) {
        int ncol = n0 + wc * 64 + n * 16 + lc;
        float bb = bias[ncol];
        int h = ncol >> 6, d = ncol & 63;
#pragma unroll
        for (int r = 0; r < 4; r++) {
          int tok = m0 + wr * 64 + m * 16 + lr * 4 + r;
          outb[(((tok >> 10) * 16 + h) * 1024 + (tok & 1023)) * 64 + d] =
              f2bf((acc[m][n][r] + bb) * scale);
        }
      }
  }
}

// ---------------- output projection, 128x64 tile -> f32, XCD-swizzled ----------------
// grid: 512 linear blocks. swz=(lin%8)*64+lin/8 -> x(16 n-blk of 64), y(32 m-blk of 128).
__global__ __launch_bounds__(256, 4) void gemmo_k(const u16* __restrict__ A,
                                                  const u16* __restrict__ Bt,
                                                  const float* __restrict__ bias,
                                                  float* __restrict__ outf) {
  const int lin = blockIdx.x;
  const int swz = (lin & 7) * 64 + (lin >> 3);
  const int x = swz & 15, y = swz >> 4;

  __shared__ __align__(16) u16 As[128 * 32];
  __shared__ __align__(16) u16 Bs[64 * 32];
  const int tid = threadIdx.x;
  const int l = tid & 63, w = tid >> 6;
  const int lr = l >> 4, lc = l & 15;
  const int wr = w >> 1, wc = w & 1;
  const int m0 = y * 128, n0 = x * 64;

  f32x4 acc[4][2] = {};
  const int sc = (tid & 3) * 8;
  const u16* Ag = A + (m0 + (tid >> 2)) * 1024 + sc;
  const u16* Bg = Bt + (n0 + (tid >> 2)) * 1024 + sc;

  for (int k0 = 0; k0 < 1024; k0 += 32) {
    __syncthreads();
    gl_lds16(Ag + k0, As + tid * 8);
    gl_lds16(Ag + 64 * 1024 + k0, As + 2048 + tid * 8);
    gl_lds16(Bg + k0, Bs + tid * 8);
    __syncthreads();
    short8 af[4], bf[2];
    const int ks8 = lr * 8;
#pragma unroll
    for (int m = 0; m < 4; m++)
      af[m] = *(const short8*)(As + (wr * 64 + m * 16 + lc) * 32 + ks8);
#pragma unroll
    for (int n = 0; n < 2; n++)
      bf[n] = *(const short8*)(Bs + (wc * 32 + n * 16 + lc) * 32 + ks8);
#pragma unroll
    for (int m = 0; m < 4; m++)
#pragma unroll
      for (int n = 0; n < 2; n++)
        acc[m][n] = MFMA16(af[m], bf[n], acc[m][n]);
  }
#pragma unroll
  for (int m = 0; m < 4; m++)
#pragma unroll
    for (int n = 0; n < 2; n++) {
      int ncol = n0 + wc * 32 + n * 16 + lc;
      float bb = bias[ncol];
#pragma unroll
      for (int r = 0; r < 4; r++) {
        int tok = m0 + wr * 64 + m * 16 + lr * 4 + r;
        outf[tok * 1024 + ncol] = acc[m][n][r] + bb;
      }
    }
}

// ---------------- flash attention: LDS-staged K/V (async DMA, swizzled) ----------------
__global__ __launch_bounds__(256, 4) void attn_k(const u16* __restrict__ Q,
                                                 const u16* __restrict__ K,
                                                 const u16* __restrict__ Vt,
                                                 u16* __restrict__ O) {
  const int bid = blockIdx.x;
  const int xcd = bid & 7, j = bid >> 3;
  const int bh = xcd + 8 * (j & 7);
  const int q0 = (j >> 3) * 64;
  const int tid = threadIdx.x;
  const int w = tid >> 6, l = tid & 63;
  const int lr = l >> 4, lc = l & 15;
  const u16* Qh = Q + bh * (1024 * 64);
  const u16* Kh = K + bh * (1024 * 64);
  const u16* Vh = Vt + bh * (64 * 1024);

  __shared__ __align__(16) u16 Ks[64 * 64];
  __shared__ __align__(16) u16 Vs[64 * 64];
  __shared__ __align__(16) u32 Plds[4][16][36];

  const int st_row = tid >> 3;
  const int st_cb = (tid & 7) * 16;
  const int sw1 = (st_cb ^ ((st_row & 7) << 4)) >> 1;
  const int st_row2 = st_row + 32;
  const int sw2 = (st_cb ^ ((st_row2 & 7) << 4)) >> 1;

  short8 bq[2];
#pragma unroll
  for (int ks = 0; ks < 2; ks++)
    bq[ks] = *(const short8*)(Qh + (q0 + w * 16 + lc) * 64 + ks * 32 + lr * 8);

  f32x4 oacc[4] = {};
  float mrun = -1e30f, lrun = 0.f;

  for (int kv0 = 0; kv0 < 1024; kv0 += 64) {
    __syncthreads();
    gl_lds16(Kh + (kv0 + st_row) * 64 + sw1, Ks + tid * 8);
    gl_lds16(Kh + (kv0 + st_row2) * 64 + sw2, Ks + 2048 + tid * 8);
    gl_lds16(Vh + st_row * 1024 + kv0 + sw1, Vs + tid * 8);
    gl_lds16(Vh + st_row2 * 1024 + kv0 + sw2, Vs + 2048 + tid * 8);
    __syncthreads();

    f32x4 s[4] = {};
#pragma unroll
    for (int mk = 0; mk < 4; mk++) {
      const int krow = mk * 16 + lc;
      const u16* kp = Ks + krow * 64;
#pragma unroll
      for (int ks = 0; ks < 2; ks++) {
        const int cb = (ks * 64 + lr * 16) ^ ((krow & 7) << 4);
        short8 ak = *(const short8*)(kp + (cb >> 1));
        s[mk] = MFMA16(ak, bq[ks], s[mk]);
      }
    }

    float mx = s[0][0];
#pragma unroll
    for (int mk = 0; mk < 4; mk++)
#pragma unroll
      for (int r = 0; r < 4; r++) mx = fmaxf(mx, s[mk][r]);
    mx = fmaxf(mx, __shfl_xor(mx, 16));
    mx = fmaxf(mx, __shfl_xor(mx, 32));
    float mnew = fmaxf(mrun, mx);
    float alpha = __expf(mrun - mnew);
    mrun = mnew;
    float ps = 0.f;
#pragma unroll
    for (int mk = 0; mk < 4; mk++)
#pragma unroll
      for (int r = 0; r < 4; r++) {
        float p = __expf(s[mk][r] - mnew);
        s[mk][r] = p;
        ps += p;
      }
    ps += __shfl_xor(ps, 16);
    ps += __shfl_xor(ps, 32);
    lrun = lrun * alpha + ps;

    u32* PW = &Plds[w][lc][0];
#pragma unroll
    for (int mk = 0; mk < 4; mk++)
#pragma unroll
      for (int rr = 0; rr < 2; rr++)
        PW[mk * 8 + lr * 2 + rr] = cvtpk(s[mk][2 * rr], s[mk][2 * rr + 1]);

    float alr[4];
#pragma unroll
    for (int r = 0; r < 4; r++) alr[r] = __shfl(alpha, lr * 4 + r);
#pragma unroll
    for (int nd = 0; nd < 4; nd++)
#pragma unroll
      for (int r = 0; r < 4; r++) oacc[nd][r] *= alr[r];

#pragma unroll
    for (int ks = 0; ks < 2; ks++) {
      short8 ap = *(const short8*)&Plds[w][lc][ks * 16 + lr * 4];
#pragma unroll
      for (int nd = 0; nd < 4; nd++) {
        const int vrow = nd * 16 + lc;
        const int cb = (ks * 64 + lr * 16) ^ ((vrow & 7) << 4);
        short8 bv = *(const short8*)(Vs + vrow * 64 + (cb >> 1));
        oacc[nd] = MFMA16(ap, bv, oacc[nd]);
      }
    }
  }

  float inv = 1.f / lrun;
  float invr[4];
#pragma unroll
  for (int r = 0; r < 4; r++) invr[r] = __shfl(inv, lr * 4 + r);
  const int b = bh >> 4, h = bh & 15;
#pragma unroll
  for (int r = 0; r < 4; r++) {
    int row = b * 1024 + q0 + w * 16 + lr * 4 + r;
#pragma unroll
    for (int nd = 0; nd < 4; nd++)
      O[row * 1024 + h * 64 + nd * 16 + lc] = f2bf(oacc[nd][r] * invr[r]);
  }
}

// ---------------- residual + LayerNorm ----------------
__global__ __launch_bounds__(256) void ln_k(const float* __restrict__ q,
                                            const float* __restrict__ p2,
                                            const float* __restrict__ gamma,
                                            const float* __restrict__ beta,
                                            float* __restrict__ out) {
  const int row = blockIdx.x, tid = threadIdx.x;
  float4 xq = ((const float4*)(q + row * 1024))[tid];
  float4 xp = ((const float4*)(p2 + row * 1024))[tid];
  float4 x = {xq.x + xp.x, xq.y + xp.y, xq.z + xp.z, xq.w + xp.w};
  float s = x.x + x.y + x.z + x.w;
#pragma unroll
  for (int off = 1; off < 64; off <<= 1) s += __shfl_xor(s, off);
  __shared__ float red[8];
  const int w = tid >> 6;
  if ((tid & 63) == 0) red[w] = s;
  __syncthreads();
  float mu = (red[0] + red[1] + red[2] + red[3]) * (1.0f / 1024.0f);
  float4 dx = {x.x - mu, x.y - mu, x.z - mu, x.w - mu};
  float s2 = dx.x * dx.x + dx.y * dx.y + dx.z * dx.z + dx.w * dx.w;
#pragma unroll
  for (int off = 1; off < 64; off <<= 1) s2 += __shfl_xor(s2, off);
  if ((tid & 63) == 0) red[4 + w] = s2;
  __syncthreads();
  float var = (red[4] + red[5] + red[6] + red[7]) * (1.0f / 1024.0f);
  float rs = rsqrtf(var + 1e-5f);
  float4 g = ((const float4*)gamma)[tid];
  float4 bb = ((const float4*)beta)[tid];
  float4 o = {dx.x * rs * g.x + bb.x, dx.y * rs * g.y + bb.y,
              dx.z * rs * g.z + bb.z, dx.w * rs * g.w + bb.w};
  ((float4*)(out + row * 1024))[tid] = o;
}

extern "C" void kernel_launch(void* const* d_in, const int* in_sizes, int n_in,
                              void* d_out, int out_size, void* d_ws, size_t ws_size,
                              hipStream_t stream) {
  const float* query = (const float*)d_in[0];
  const float* kv    = (const float*)d_in[1];
  const float* Wq = (const float*)d_in[2];
  const float* bq = (const float*)d_in[3];
  const float* Wk = (const float*)d_in[4];
  const float* bk = (const float*)d_in[5];
  const float* Wv = (const float*)d_in[6];
  const float* bv = (const float*)d_in[7];
  const float* Wo = (const float*)d_in[8];
  const float* bo = (const float*)d_in[9];
  const float* gamma = (const float*)d_in[10];
  const float* beta  = (const float*)d_in[11];
  float* out = (float*)d_out;

  char* ws = (char*)d_ws;
  const size_t MB = 1u << 20;
  u16* qbf  = (u16*)(ws + 0 * MB);
  u16* kvbf = (u16*)(ws + 8 * MB);
  u16* Wqt  = (u16*)(ws + 16 * MB);
  u16* Wkt  = (u16*)(ws + 18 * MB);
  u16* Wvt  = (u16*)(ws + 20 * MB);
  u16* Wot  = (u16*)(ws + 22 * MB);
  u16* Qh   = (u16*)(ws + 24 * MB);
  u16* Kh   = (u16*)(ws + 32 * MB);
  u16* Vth  = (u16*)(ws + 40 * MB);
  u16* attO = (u16*)(ws + 48 * MB);
  float* p2 = (float*)(ws + 56 * MB);

  cvt_bf16_k<<<dim3(4096), dim3(256), 0, stream>>>(query, qbf);
  cvt_bf16_k<<<dim3(4096), dim3(256), 0, stream>>>(kv, kvbf);
  wt_k<<<dim3(16, 16, 4), dim3(256), 0, stream>>>(Wq, Wk, Wv, Wo, Wqt, Wkt, Wvt, Wot);

  gemmqkv_k<<<dim3(768), dim3(256), 0, stream>>>(qbf, kvbf, Wqt, Wkt, Wvt,
                                                 bq, bk, bv, Qh, Kh, Vth);

  attn_k<<<dim3(1024), dim3(256), 0, stream>>>(Qh, Kh, Vth, attO);

  gemmo_k<<<dim3(512), dim3(256), 0, stream>>>(attO, Wot, bo, p2);

  ln_k<<<dim3(4096), dim3(256), 0, stream>>>(query, p2, gamma, beta, out);
}